// Round 17
// baseline (177.820 us; speedup 1.0000x reference)
//
#include <hip/hip_runtime.h>
#include <stdint.h>

// Match numpy op-for-op rounding: no FMA contraction anywhere.
#pragma clang fp contract(off)

#define BATCH 8
#define HH 64
#define WW 64
#define KA 9
#define NBOX (HH * WW * KA)   // 36864 per batch
#define TOPN 2000
#define NPAD 2048
#define NW 32                 // 64-bit words covering 2048 bits
#define IOU_T 0.7f
#define MINSZ 0.01f
#define EPSF 1e-7f
#define CANDCAP 3072          // candidate buffer (expected ~2300 for uniform)

typedef unsigned int u32;
typedef unsigned long long u64;

__device__ __forceinline__ float clamp01(float x) { return fminf(fmaxf(x, 0.0f), 1.0f); }

// ---------------------------------------------------------------------------
// Shared box decode (bit-exact same arithmetic everywhere; contract off).
// ---------------------------------------------------------------------------
__device__ __forceinline__ void decode_one(
    const float* __restrict__ scores, const float4* __restrict__ offsets,
    const float* __restrict__ anchors, int gid, int t,
    float4* boxOut, u32* keyOut)
{
    int k = t % KA;
    int pos = t / KA;
    int wx = pos & (WW - 1);
    int hy = pos >> 6;
    float s = scores[gid];
    float4 off = offsets[gid];
    float aw = anchors[2 * k], ah = anchors[2 * k + 1];
    float cx = ((float)wx + 0.5f) * 16.0f;
    float cy = ((float)hy + 0.5f) * 16.0f;
    float pw = (expf(off.z) * aw) / 1024.0f;   // exp(off)*anc/img_wh
    float ph = (expf(off.w) * ah) / 1024.0f;
    float xc = (aw * off.x + cx) / 1024.0f;    // (anc*off + center)/img_wh
    float yc = (ah * off.y + cy) / 1024.0f;
    float x1 = clamp01(xc - pw * 0.5f);
    float y1 = clamp01(yc - ph * 0.5f);
    float x2 = clamp01(xc + pw * 0.5f);
    float y2 = clamp01(yc + ph * 0.5f);
    float sc = clamp01(s);
    float m = ((x2 - x1) > MINSZ && (y2 - y1) > MINSZ) ? 1.0f : 0.0f;
    *boxOut = make_float4(x1 * m, y1 * m, x2 * m, y2 * m);
    *keyOut = __float_as_uint(sc * m);   // score >= 0: bit order == value order
}

// ---------------------------------------------------------------------------
// 0) Zero the global 12-bit histograms (8 x 4096 bins).
// ---------------------------------------------------------------------------
__global__ __launch_bounds__(256) void zero_kernel(uint4* __restrict__ p, int n)
{
    int g = blockIdx.x * 256 + threadIdx.x;
    if (g < n) p[g] = make_uint4(0, 0, 0, 0);
}

// ---------------------------------------------------------------------------
// 1) Decode score keys + per-block LDS histogram, merged to global with ONE
//    atomic per nonzero bin per block (skew-tolerant).
// ---------------------------------------------------------------------------
__global__ __launch_bounds__(256) void decode_kernel(
    const float* __restrict__ scores, const float4* __restrict__ offsets,
    const float* __restrict__ anchors, u32* __restrict__ keys,
    u32* __restrict__ ghist)
{
    __shared__ u32 lhist[4096];
    for (int i = threadIdx.x; i < 4096; i += 256) lhist[i] = 0;
    __syncthreads();

    int gid = blockIdx.x * 256 + threadIdx.x;   // grid exactly covers 8*NBOX
    int b = gid / NBOX;                         // uniform per block (256|NBOX)
    int t = gid - b * NBOX;
    float4 box; u32 key;
    decode_one(scores, offsets, anchors, gid, t, &box, &key);
    keys[gid] = key;
    atomicAdd(&lhist[key >> 20], 1u);
    __syncthreads();

    for (int i = threadIdx.x; i < 4096; i += 256) {
        u32 v = lhist[i];
        if (v) atomicAdd(&ghist[(b << 12) + i], v);
    }
}

// ---------------------------------------------------------------------------
// Wave-level descending rank-find over a 4096-bin LDS hist: 2 barriers.
// ---------------------------------------------------------------------------
__device__ __forceinline__ void rank_find_4096(
    const u32* __restrict__ histL, u32* __restrict__ partial,
    int r, u32* Bsh, int* Rsh, int tid)
{
    partial[tid] = histL[4 * tid] + histL[4 * tid + 1]
                 + histL[4 * tid + 2] + histL[4 * tid + 3];
    __syncthreads();
    if (tid < 64) {
        int lane = tid;
        u32 s = 0;
#pragma unroll
        for (int q = 0; q < 16; ++q) s += partial[lane * 16 + q];
        u32 suf = s;
#pragma unroll
        for (int d = 1; d < 64; d <<= 1) {
            u32 t = __shfl_down(suf, d);
            if (lane + d < 64) suf += t;
        }
        u32 nxt = __shfl_down(suf, 1);
        if (lane == 63) nxt = 0;
        bool cross = (suf >= (u32)r) && (nxt < (u32)r);   // exactly one lane
        u64 bal = __ballot(cross);
        int L = (int)(__ffsll((unsigned long long)bal) - 1);
        u32 above = __shfl(nxt, L);       // count strictly above superseg L
        u32 hv = histL[64 * L + lane];
        u32 suf2 = hv;
#pragma unroll
        for (int d = 1; d < 64; d <<= 1) {
            u32 t = __shfl_down(suf2, d);
            if (lane + d < 64) suf2 += t;
        }
        u32 nxt2 = __shfl_down(suf2, 1);
        if (lane == 63) nxt2 = 0;
        u32 mine2 = suf2 + above;
        nxt2 += above;
        if (mine2 >= (u32)r && nxt2 < (u32)r) {
            *Bsh = (u32)(64 * L + lane);
            *Rsh = r - (int)nxt2;
        }
    }
    __syncthreads();
}

// ---------------------------------------------------------------------------
// 2) Per-batch select (fused, one block per batch): global hist -> P1/r1;
//    single uint4 stream splits definite -> sel / candidates -> cand;
//    3x12-bit LDS radix over cand -> exact unique T48; append exactly r1;
//    in-register bitonic sort 2048 desc; decode top-2000 boxes.
// ---------------------------------------------------------------------------
__global__ __launch_bounds__(1024) void select_kernel(
    const u32* __restrict__ keys, const u32* __restrict__ ghist,
    const float* __restrict__ scores, const float4* __restrict__ offsets,
    const float* __restrict__ anchors, float4* __restrict__ topBoxes)
{
    int b = blockIdx.x;
    int tid = threadIdx.x;
    int lane = tid & 63;
    const u32* kb = keys + (size_t)b * NBOX;

    __shared__ u32 hist[4096];    // 16 KB
    __shared__ u32 partial[1024]; //  4 KB
    __shared__ u64 sel[NPAD];     // 16 KB
    __shared__ u64 cand[CANDCAP]; // 24 KB  (total ~60.5 KB)
    __shared__ u32 Bsh;
    __shared__ int Rsh;
    __shared__ int ctr, cctr;

    // ---- load global hist; find P1/r1 ----
    if (tid == 0) { ctr = 0; cctr = 0; }
    for (int i = tid; i < 4096; i += 1024) hist[i] = ghist[(b << 12) + i];
    for (int i = tid; i < NPAD; i += 1024) sel[i] = 0ull;
    __syncthreads();
    rank_find_4096(hist, partial, TOPN, &Bsh, &Rsh, tid);
    u32 P1 = Bsh;
    int r1 = Rsh;          // need top-r1 of the candidates (top12 == P1)
    __syncthreads();

    // ---- single uint4 stream: definite -> sel, candidates -> cand ----
    const uint4* kb4 = (const uint4*)kb;
#pragma unroll 1
    for (int it = 0; it < NBOX / 4096; ++it) {
        int i4 = it * 1024 + tid;           // uint4 index
        uint4 kv = kb4[i4];
        u32 karr[4] = { kv.x, kv.y, kv.z, kv.w };
        u64 bd[4], bc[4];
        int totd = 0, totc = 0;
#pragma unroll
        for (int q = 0; q < 4; ++q) {
            u32 top = karr[q] >> 20;
            bd[q] = __ballot(top > P1);
            bc[q] = __ballot(top == P1);
            totd += (int)__popcll(bd[q]);
            totc += (int)__popcll(bc[q]);
        }
        int based = 0, basec = 0;
        if (lane == 0) {
            if (totd) based = atomicAdd(&ctr, totd);
            if (totc) basec = atomicAdd(&cctr, totc);
        }
        based = __shfl(based, 0);
        basec = __shfl(basec, 0);
        u64 lmask = (1ull << lane) - 1ull;
        int offd = 0, offc = 0;
#pragma unroll
        for (int q = 0; q < 4; ++q) {
            u32 key = karr[q];
            int i = i4 * 4 + q;
            u64 K = ((u64)key << 16) | (u64)(0xFFFFu - (u32)i);
            u32 top = key >> 20;
            if (top > P1) {
                int slot = based + offd + (int)__popcll(bd[q] & lmask);
                if (slot < NPAD) sel[slot] = K;
            } else if (top == P1) {
                int cslot = basec + offc + (int)__popcll(bc[q] & lmask);
                if (cslot < CANDCAP) cand[cslot] = K;
            }
            offd += (int)__popcll(bd[q]);
            offc += (int)__popcll(bc[q]);
        }
    }
    __syncthreads();
    int cc = cctr < CANDCAP ? cctr : CANDCAP;

    // ---- 3x12-bit LDS radix over candidates: exact T48 ----
    u64 prefix = (u64)P1;               // == K>>36 for every candidate
    int r = r1;
    for (int p = 0; p < 3; ++p) {
        int shift = 24 - 12 * p;
        for (int i = tid; i < 4096; i += 1024) hist[i] = 0;
        __syncthreads();
        for (int c = tid; c < cc; c += 1024) {
            u64 K = cand[c];
            if ((K >> (shift + 12)) == prefix)
                atomicAdd(&hist[(u32)((K >> shift) & 0xFFFull)], 1u);
        }
        __syncthreads();
        rank_find_4096(hist, partial, r, &Bsh, &Rsh, tid);
        prefix = (prefix << 12) | (u64)Bsh;
        r = Rsh;
        __syncthreads();
    }
    u64 T48 = prefix;   // exact r1-th largest candidate key (unique keys)

    // append exactly r1 candidates >= T48
    for (int c = tid; c < cc; c += 1024) {
        u64 K = cand[c];
        bool take = (K >= T48);
        u64 bal = __ballot(take);
        int base = 0;
        if (lane == 0 && bal) base = atomicAdd(&ctr, (int)__popcll(bal));
        base = __shfl(base, 0);
        if (take) {
            int slot = base + (int)__popcll(bal & ((1ull << lane) - 1ull));
            if (slot < NPAD) sel[slot] = K;
        }
    }
    __syncthreads();

    // ---- bitonic sort 2048 desc, register-resident ----
    u64 e0 = sel[tid];
    u64 e1 = sel[tid + 1024];
    const int i0 = tid, i1 = tid + 1024;

    for (int k = 2; k <= NPAD; k <<= 1) {
        for (int j = k >> 1; j >= 64; j >>= 1) {
            if (j == 1024) {
                u64 mx = e0 > e1 ? e0 : e1;
                u64 mn = e0 > e1 ? e1 : e0;
                e0 = mx; e1 = mn;
            } else {
                sel[i0] = e0; sel[i1] = e1;
                __syncthreads();
                u64 p0 = sel[i0 ^ j];
                u64 p1 = sel[i1 ^ j];
                bool kp0 = ((i0 & k) == 0) ^ ((i0 & j) != 0);
                bool kp1 = ((i1 & k) == 0) ^ ((i1 & j) != 0);
                e0 = kp0 ? (e0 > p0 ? e0 : p0) : (e0 < p0 ? e0 : p0);
                e1 = kp1 ? (e1 > p1 ? e1 : p1) : (e1 < p1 ? e1 : p1);
                __syncthreads();
            }
        }
        int jstart = (k >> 1) < 32 ? (k >> 1) : 32;
        for (int j = jstart; j >= 1; j >>= 1) {
            u64 p0 = __shfl_xor(e0, j);
            u64 p1 = __shfl_xor(e1, j);
            bool kp0 = ((i0 & k) == 0) ^ ((i0 & j) != 0);
            bool kp1 = ((i1 & k) == 0) ^ ((i1 & j) != 0);
            e0 = kp0 ? (e0 > p0 ? e0 : p0) : (e0 < p0 ? e0 : p0);
            e1 = kp1 ? (e1 > p1 ? e1 : p1) : (e1 < p1 ? e1 : p1);
        }
    }

    // ---- epilogue: decode top-2000 boxes straight from registers ----
    {
        float4 v; u32 kd;
        int idx = 0xFFFF - (int)(e0 & 0xFFFFull);
        decode_one(scores, offsets, anchors, b * NBOX + idx, idx, &v, &kd);
        topBoxes[b * NPAD + i0] = v;
    }
    {
        float4 v = make_float4(0, 0, 0, 0);
        if (i1 < TOPN) {
            u32 kd;
            int idx = 0xFFFF - (int)(e1 & 0xFFFFull);
            decode_one(scores, offsets, anchors, b * NBOX + idx, idx, &v, &kd);
        }
        topBoxes[b * NPAD + i1] = v;
    }
}

// ---------------------------------------------------------------------------
// 3) Suppression bitmask, upper triangle only. Each wave = one row. The row's
//    32 mask words are kept in per-lane registers (lane w holds word w) and
//    written out ONLY if the row suppresses anything (one coalesced 256 B
//    store). rowNZ[r] byte marks suppressor rows for resolve.
// ---------------------------------------------------------------------------
__global__ __launch_bounds__(256) void iou_kernel(
    const float4* __restrict__ topBoxes, u64* __restrict__ sup,
    unsigned char* __restrict__ rowNZ)
{
    int gid = blockIdx.x * 256 + threadIdx.x;
    int wid = gid >> 6;
    int lane = gid & 63;
    int b = wid / TOPN;
    int r = wid - b * TOPN;

    float4 A = topBoxes[(size_t)b * NPAD + r];
    float areaA = (A.z - A.x) * (A.w - A.y);
    size_t supBase = ((size_t)b * NPAD + r) * NW;

    u64 msave = 0, anyM = 0;
    for (int w = r >> 6; w < NW; ++w) {
        int j = w * 64 + lane;
        float4 Bx = topBoxes[(size_t)b * NPAD + j];
        float ix1 = fmaxf(A.x, Bx.x);
        float iy1 = fmaxf(A.y, Bx.y);
        float ix2 = fminf(A.z, Bx.z);
        float iy2 = fminf(A.w, Bx.w);
        float iw = fmaxf(ix2 - ix1, 0.0f);
        float ih = fmaxf(iy2 - iy1, 0.0f);
        float inter = iw * ih;
        float areaB = (Bx.z - Bx.x) * (Bx.w - Bx.y);
        float iou = inter / (areaA + areaB - inter + EPSF);
        bool s = (iou > IOU_T) && (j > r) && (j < TOPN);
        u64 m = __ballot(s);
        anyM |= m;
        if (lane == w) msave = m;     // lane w owns word w (w < 32)
    }
    if (lane == 0) rowNZ[(size_t)b * NPAD + r] = anyM ? 1 : 0;
    if (anyM && lane < NW) sup[supBase + lane] = msave;   // 256 B coalesced
}

// ---------------------------------------------------------------------------
// 4) Resolve: suppressor-list serial pass. The full 2048-bit keep vector
//    lives in wave 0's registers (u32/lane). Only rows with rowNZ set are
//    visited (ascending); per step: readlane keep bit -> conditional
//    wave-wide AND of the prefetched row mask (8-deep pipeline, loads are
//    keep-independent). Exact greedy semantics: zero-mask rows are identity
//    steps; suppressed suppressors are skipped via their keep bit.
// ---------------------------------------------------------------------------
__global__ __launch_bounds__(256) void resolve_kernel(
    const u64* __restrict__ sup, const unsigned char* __restrict__ rowNZ,
    const float4* __restrict__ topBoxes, float4* __restrict__ out)
{
    int b = blockIdx.x;
    int tid = threadIdx.x;
    int lane = tid & 63;
    int wv = tid >> 6;

    __shared__ unsigned short supList[TOPN];
    __shared__ int wt[4];
    __shared__ int chunkBase;
    __shared__ u32 keep32[64];
    __shared__ int wbase[NW];

    if (tid == 0) chunkBase = 0;
    __syncthreads();

    // ---- Phase A: ordered compaction of suppressor row indices ----
    const unsigned char* nzB = rowNZ + (size_t)b * NPAD;
    for (int c = 0; c < 8; ++c) {
        int r = c * 256 + tid;
        bool nz = (r < TOPN) && (nzB[r] != 0);
        u64 bal = __ballot(nz);
        if (lane == 0) wt[wv] = (int)__popcll(bal);
        __syncthreads();
        int before = 0;
        for (int q = 0; q < wv; ++q) before += wt[q];
        if (nz) {
            int slot = chunkBase + before + (int)__popcll(bal & ((1ull << lane) - 1ull));
            supList[slot] = (unsigned short)r;
        }
        __syncthreads();
        if (tid == 0) chunkBase += wt[0] + wt[1] + wt[2] + wt[3];
        __syncthreads();
    }
    int S = chunkBase;

    // ---- Phase B: wave 0 serial pass over suppressors, keep in registers ----
    if (tid < 64) {
        u32 kseg = (lane < 62) ? 0xFFFFFFFFu : (lane == 62 ? 0xFFFFu : 0u);
        const u32* rows = (const u32*)(sup + (size_t)b * NPAD * NW);

#define LOADG(dst, pos) dst = ((pos) < S) ? rows[(size_t)supList[(pos)] * 64 + lane] : 0u;
#define STEP(cc, pos)                                                          \
        if ((pos) < S) {                                                       \
            int ii = supList[(pos)];                                           \
            u32 bit = (u32)__builtin_amdgcn_readlane((int)kseg, ii >> 5)       \
                      & (1u << (ii & 31));                                     \
            if (bit) kseg &= ~(cc);                                            \
        }

        u32 c0, c1, c2, c3, c4, c5, c6, c7;
        LOADG(c0, 0) LOADG(c1, 1) LOADG(c2, 2) LOADG(c3, 3)
        LOADG(c4, 4) LOADG(c5, 5) LOADG(c6, 6) LOADG(c7, 7)
        for (int g = 0; g < S; g += 8) {
            u32 n0, n1, n2, n3, n4, n5, n6, n7;
            LOADG(n0, g + 8)  LOADG(n1, g + 9)  LOADG(n2, g + 10) LOADG(n3, g + 11)
            LOADG(n4, g + 12) LOADG(n5, g + 13) LOADG(n6, g + 14) LOADG(n7, g + 15)
            STEP(c0, g)     STEP(c1, g + 1) STEP(c2, g + 2) STEP(c3, g + 3)
            STEP(c4, g + 4) STEP(c5, g + 5) STEP(c6, g + 6) STEP(c7, g + 7)
            c0 = n0; c1 = n1; c2 = n2; c3 = n3;
            c4 = n4; c5 = n5; c6 = n6; c7 = n7;
        }
#undef LOADG
#undef STEP
        keep32[lane] = kseg;
    }
    __syncthreads();

    // ---- Phase C: prefix + scatter kept boxes in index order ----
    const u64* keep64 = (const u64*)keep32;
    if (tid == 0) {
        int s = 0;
        for (int w2 = 0; w2 < NW; ++w2) { wbase[w2] = s; s += __popcll(keep64[w2]); }
    }
    __syncthreads();
    for (int i = tid; i < TOPN; i += 256)
        out[(size_t)b * TOPN + i] = make_float4(0, 0, 0, 0);
    __syncthreads();
    for (int i = tid; i < TOPN; i += 256) {
        int wi = i >> 6, bz = i & 63;
        u64 kw = keep64[wi];
        if ((kw >> bz) & 1ull) {
            int pos = wbase[wi] + __popcll(kw & ((1ull << bz) - 1ull));
            out[(size_t)b * TOPN + pos] = topBoxes[(size_t)b * NPAD + i];
        }
    }
}

// ---------------------------------------------------------------------------
// Workspace layout (bytes):
//   sup      : 0           size 8*2048*32*8 = 4,194,304
//   keys     : 4,194,304   size 8*36864*4   = 1,179,648
//   topBoxes : 5,373,952   size 8*2048*16   =   262,144
//   ghist    : 5,636,096   size 8*4096*4    =   131,072  (zeroed each call)
//   rowNZ    : 5,767,168   size 8*2048*1    =    16,384  (fully rewritten)
//   total    : 5,783,552 (~5.5 MB)
// ---------------------------------------------------------------------------
extern "C" void kernel_launch(void* const* d_in, const int* in_sizes, int n_in,
                              void* d_out, int out_size, void* d_ws, size_t ws_size,
                              hipStream_t stream)
{
    const float*  scores  = (const float*)d_in[0];
    const float4* offsets = (const float4*)d_in[1];
    const float*  anchors = (const float*)d_in[2];
    float4* out = (float4*)d_out;

    char* ws = (char*)d_ws;
    u64*           sup      = (u64*)(ws);
    u32*           keys     = (u32*)(ws + 4194304);
    float4*        topBoxes = (float4*)(ws + 5373952);
    u32*           ghist    = (u32*)(ws + 5636096);
    unsigned char* rowNZ    = (unsigned char*)(ws + 5767168);

    zero_kernel<<<(131072 / 16 + 255) / 256, 256, 0, stream>>>((uint4*)ghist, 131072 / 16);
    decode_kernel<<<(BATCH * NBOX) / 256, 256, 0, stream>>>(scores, offsets, anchors, keys, ghist);
    select_kernel<<<BATCH, 1024, 0, stream>>>(keys, ghist, scores, offsets, anchors, topBoxes);
    iou_kernel<<<(BATCH * TOPN * 64) / 256, 256, 0, stream>>>(topBoxes, sup, rowNZ);
    resolve_kernel<<<BATCH, 256, 0, stream>>>(sup, rowNZ, topBoxes, out);
}

// Round 18
// 114.578 us; speedup vs baseline: 1.5520x; 1.5520x over previous
//
#include <hip/hip_runtime.h>
#include <stdint.h>

// Match numpy op-for-op rounding: no FMA contraction anywhere.
#pragma clang fp contract(off)

#define BATCH 8
#define HH 64
#define WW 64
#define KA 9
#define NBOX (HH * WW * KA)   // 36864 per batch
#define TOPN 2000
#define NPAD 2048
#define NW 32                 // 64-bit words covering 2048 bits
#define IOU_T 0.7f
#define MINSZ 0.01f
#define EPSF 1e-7f
#define TSTRIDE 33            // LDS tile row stride in u64 (bank-conflict-free)
#define CANDCAP 3072          // candidate buffer (expected ~2300 for uniform)

typedef unsigned int u32;
typedef unsigned long long u64;

__device__ __forceinline__ float clamp01(float x) { return fminf(fmaxf(x, 0.0f), 1.0f); }

// Workgroup barrier with LDS-only drain: does NOT wait vmcnt, so global
// prefetch loads stay in flight across the barrier.
__device__ __forceinline__ void bar_lds()
{
    asm volatile("s_waitcnt lgkmcnt(0)" ::: "memory");
    __builtin_amdgcn_s_barrier();
}

// ---------------------------------------------------------------------------
// Shared box decode (bit-exact same arithmetic everywhere; contract off).
// ---------------------------------------------------------------------------
__device__ __forceinline__ void decode_one(
    const float* __restrict__ scores, const float4* __restrict__ offsets,
    const float* __restrict__ anchors, int gid, int t,
    float4* boxOut, u32* keyOut)
{
    int k = t % KA;
    int pos = t / KA;
    int wx = pos & (WW - 1);
    int hy = pos >> 6;
    float s = scores[gid];
    float4 off = offsets[gid];
    float aw = anchors[2 * k], ah = anchors[2 * k + 1];
    float cx = ((float)wx + 0.5f) * 16.0f;
    float cy = ((float)hy + 0.5f) * 16.0f;
    float pw = (expf(off.z) * aw) / 1024.0f;   // exp(off)*anc/img_wh
    float ph = (expf(off.w) * ah) / 1024.0f;
    float xc = (aw * off.x + cx) / 1024.0f;    // (anc*off + center)/img_wh
    float yc = (ah * off.y + cy) / 1024.0f;
    float x1 = clamp01(xc - pw * 0.5f);
    float y1 = clamp01(yc - ph * 0.5f);
    float x2 = clamp01(xc + pw * 0.5f);
    float y2 = clamp01(yc + ph * 0.5f);
    float sc = clamp01(s);
    float m = ((x2 - x1) > MINSZ && (y2 - y1) > MINSZ) ? 1.0f : 0.0f;
    *boxOut = make_float4(x1 * m, y1 * m, x2 * m, y2 * m);
    *keyOut = __float_as_uint(sc * m);   // score >= 0: bit order == value order
}

// ---------------------------------------------------------------------------
// 0) Zero the global 12-bit histograms (8 x 4096 bins).
// ---------------------------------------------------------------------------
__global__ __launch_bounds__(256) void zero_kernel(uint4* __restrict__ p, int n)
{
    int g = blockIdx.x * 256 + threadIdx.x;
    if (g < n) p[g] = make_uint4(0, 0, 0, 0);
}

// ---------------------------------------------------------------------------
// 1) Decode score keys + per-block LDS histogram, merged to global with ONE
//    atomic per nonzero bin per block (skew-tolerant).
// ---------------------------------------------------------------------------
__global__ __launch_bounds__(256) void decode_kernel(
    const float* __restrict__ scores, const float4* __restrict__ offsets,
    const float* __restrict__ anchors, u32* __restrict__ keys,
    u32* __restrict__ ghist)
{
    __shared__ u32 lhist[4096];
    for (int i = threadIdx.x; i < 4096; i += 256) lhist[i] = 0;
    __syncthreads();

    int gid = blockIdx.x * 256 + threadIdx.x;   // grid exactly covers 8*NBOX
    int b = gid / NBOX;                         // uniform per block (256|NBOX)
    int t = gid - b * NBOX;
    float4 box; u32 key;
    decode_one(scores, offsets, anchors, gid, t, &box, &key);
    keys[gid] = key;
    atomicAdd(&lhist[key >> 20], 1u);
    __syncthreads();

    for (int i = threadIdx.x; i < 4096; i += 256) {
        u32 v = lhist[i];
        if (v) atomicAdd(&ghist[(b << 12) + i], v);
    }
}

// ---------------------------------------------------------------------------
// Wave-level descending rank-find over a 4096-bin LDS hist: 2 barriers.
// ---------------------------------------------------------------------------
__device__ __forceinline__ void rank_find_4096(
    const u32* __restrict__ histL, u32* __restrict__ partial,
    int r, u32* Bsh, int* Rsh, int tid)
{
    partial[tid] = histL[4 * tid] + histL[4 * tid + 1]
                 + histL[4 * tid + 2] + histL[4 * tid + 3];
    __syncthreads();
    if (tid < 64) {
        int lane = tid;
        u32 s = 0;
#pragma unroll
        for (int q = 0; q < 16; ++q) s += partial[lane * 16 + q];
        u32 suf = s;
#pragma unroll
        for (int d = 1; d < 64; d <<= 1) {
            u32 t = __shfl_down(suf, d);
            if (lane + d < 64) suf += t;
        }
        u32 nxt = __shfl_down(suf, 1);
        if (lane == 63) nxt = 0;
        bool cross = (suf >= (u32)r) && (nxt < (u32)r);   // exactly one lane
        u64 bal = __ballot(cross);
        int L = (int)(__ffsll((unsigned long long)bal) - 1);
        u32 above = __shfl(nxt, L);       // count strictly above superseg L
        u32 hv = histL[64 * L + lane];
        u32 suf2 = hv;
#pragma unroll
        for (int d = 1; d < 64; d <<= 1) {
            u32 t = __shfl_down(suf2, d);
            if (lane + d < 64) suf2 += t;
        }
        u32 nxt2 = __shfl_down(suf2, 1);
        if (lane == 63) nxt2 = 0;
        u32 mine2 = suf2 + above;
        nxt2 += above;
        if (mine2 >= (u32)r && nxt2 < (u32)r) {
            *Bsh = (u32)(64 * L + lane);
            *Rsh = r - (int)nxt2;
        }
    }
    __syncthreads();
}

// ---------------------------------------------------------------------------
// 2) Per-batch select (fused, one block per batch): global hist -> P1/r1;
//    single uint4 stream splits definite -> sel / candidates -> cand;
//    3x12-bit LDS radix over cand -> exact unique T48; append exactly r1;
//    in-register bitonic sort 2048 desc; decode top-2000 boxes.
// ---------------------------------------------------------------------------
__global__ __launch_bounds__(1024) void select_kernel(
    const u32* __restrict__ keys, const u32* __restrict__ ghist,
    const float* __restrict__ scores, const float4* __restrict__ offsets,
    const float* __restrict__ anchors, float4* __restrict__ topBoxes)
{
    int b = blockIdx.x;
    int tid = threadIdx.x;
    int lane = tid & 63;
    const u32* kb = keys + (size_t)b * NBOX;

    __shared__ u32 hist[4096];    // 16 KB
    __shared__ u32 partial[1024]; //  4 KB
    __shared__ u64 sel[NPAD];     // 16 KB
    __shared__ u64 cand[CANDCAP]; // 24 KB  (total ~60.5 KB)
    __shared__ u32 Bsh;
    __shared__ int Rsh;
    __shared__ int ctr, cctr;

    // ---- load global hist; find P1/r1 ----
    if (tid == 0) { ctr = 0; cctr = 0; }
    for (int i = tid; i < 4096; i += 1024) hist[i] = ghist[(b << 12) + i];
    for (int i = tid; i < NPAD; i += 1024) sel[i] = 0ull;
    __syncthreads();
    rank_find_4096(hist, partial, TOPN, &Bsh, &Rsh, tid);
    u32 P1 = Bsh;
    int r1 = Rsh;          // need top-r1 of the candidates (top12 == P1)
    __syncthreads();

    // ---- single uint4 stream: definite -> sel, candidates -> cand ----
    const uint4* kb4 = (const uint4*)kb;
#pragma unroll 1
    for (int it = 0; it < NBOX / 4096; ++it) {
        int i4 = it * 1024 + tid;           // uint4 index
        uint4 kv = kb4[i4];
        u32 karr[4] = { kv.x, kv.y, kv.z, kv.w };
        u64 bd[4], bc[4];
        int totd = 0, totc = 0;
#pragma unroll
        for (int q = 0; q < 4; ++q) {
            u32 top = karr[q] >> 20;
            bd[q] = __ballot(top > P1);
            bc[q] = __ballot(top == P1);
            totd += (int)__popcll(bd[q]);
            totc += (int)__popcll(bc[q]);
        }
        int based = 0, basec = 0;
        if (lane == 0) {
            if (totd) based = atomicAdd(&ctr, totd);
            if (totc) basec = atomicAdd(&cctr, totc);
        }
        based = __shfl(based, 0);
        basec = __shfl(basec, 0);
        u64 lmask = (1ull << lane) - 1ull;
        int offd = 0, offc = 0;
#pragma unroll
        for (int q = 0; q < 4; ++q) {
            u32 key = karr[q];
            int i = i4 * 4 + q;
            u64 K = ((u64)key << 16) | (u64)(0xFFFFu - (u32)i);
            u32 top = key >> 20;
            if (top > P1) {
                int slot = based + offd + (int)__popcll(bd[q] & lmask);
                if (slot < NPAD) sel[slot] = K;
            } else if (top == P1) {
                int cslot = basec + offc + (int)__popcll(bc[q] & lmask);
                if (cslot < CANDCAP) cand[cslot] = K;
            }
            offd += (int)__popcll(bd[q]);
            offc += (int)__popcll(bc[q]);
        }
    }
    __syncthreads();
    int cc = cctr < CANDCAP ? cctr : CANDCAP;

    // ---- 3x12-bit LDS radix over candidates: exact T48 ----
    u64 prefix = (u64)P1;               // == K>>36 for every candidate
    int r = r1;
    for (int p = 0; p < 3; ++p) {
        int shift = 24 - 12 * p;
        for (int i = tid; i < 4096; i += 1024) hist[i] = 0;
        __syncthreads();
        for (int c = tid; c < cc; c += 1024) {
            u64 K = cand[c];
            if ((K >> (shift + 12)) == prefix)
                atomicAdd(&hist[(u32)((K >> shift) & 0xFFFull)], 1u);
        }
        __syncthreads();
        rank_find_4096(hist, partial, r, &Bsh, &Rsh, tid);
        prefix = (prefix << 12) | (u64)Bsh;
        r = Rsh;
        __syncthreads();
    }
    u64 T48 = prefix;   // exact r1-th largest candidate key (unique keys)

    // append exactly r1 candidates >= T48
    for (int c = tid; c < cc; c += 1024) {
        u64 K = cand[c];
        bool take = (K >= T48);
        u64 bal = __ballot(take);
        int base = 0;
        if (lane == 0 && bal) base = atomicAdd(&ctr, (int)__popcll(bal));
        base = __shfl(base, 0);
        if (take) {
            int slot = base + (int)__popcll(bal & ((1ull << lane) - 1ull));
            if (slot < NPAD) sel[slot] = K;
        }
    }
    __syncthreads();

    // ---- bitonic sort 2048 desc, register-resident ----
    u64 e0 = sel[tid];
    u64 e1 = sel[tid + 1024];
    const int i0 = tid, i1 = tid + 1024;

    for (int k = 2; k <= NPAD; k <<= 1) {
        for (int j = k >> 1; j >= 64; j >>= 1) {
            if (j == 1024) {
                u64 mx = e0 > e1 ? e0 : e1;
                u64 mn = e0 > e1 ? e1 : e0;
                e0 = mx; e1 = mn;
            } else {
                sel[i0] = e0; sel[i1] = e1;
                __syncthreads();
                u64 p0 = sel[i0 ^ j];
                u64 p1 = sel[i1 ^ j];
                bool kp0 = ((i0 & k) == 0) ^ ((i0 & j) != 0);
                bool kp1 = ((i1 & k) == 0) ^ ((i1 & j) != 0);
                e0 = kp0 ? (e0 > p0 ? e0 : p0) : (e0 < p0 ? e0 : p0);
                e1 = kp1 ? (e1 > p1 ? e1 : p1) : (e1 < p1 ? e1 : p1);
                __syncthreads();
            }
        }
        int jstart = (k >> 1) < 32 ? (k >> 1) : 32;
        for (int j = jstart; j >= 1; j >>= 1) {
            u64 p0 = __shfl_xor(e0, j);
            u64 p1 = __shfl_xor(e1, j);
            bool kp0 = ((i0 & k) == 0) ^ ((i0 & j) != 0);
            bool kp1 = ((i1 & k) == 0) ^ ((i1 & j) != 0);
            e0 = kp0 ? (e0 > p0 ? e0 : p0) : (e0 < p0 ? e0 : p0);
            e1 = kp1 ? (e1 > p1 ? e1 : p1) : (e1 < p1 ? e1 : p1);
        }
    }

    // ---- epilogue: decode top-2000 boxes straight from registers ----
    {
        float4 v; u32 kd;
        int idx = 0xFFFF - (int)(e0 & 0xFFFFull);
        decode_one(scores, offsets, anchors, b * NBOX + idx, idx, &v, &kd);
        topBoxes[b * NPAD + i0] = v;
    }
    {
        float4 v = make_float4(0, 0, 0, 0);
        if (i1 < TOPN) {
            u32 kd;
            int idx = 0xFFFF - (int)(e1 & 0xFFFFull);
            decode_one(scores, offsets, anchors, b * NBOX + idx, idx, &v, &kd);
        }
        topBoxes[b * NPAD + i1] = v;
    }
}

// ---------------------------------------------------------------------------
// 3) Suppression bitmask, upper triangle only. Each wave = one row; lane w
//    holds word w in registers; the 256 B row is stored ONLY if the row
//    suppresses anything. rowNZ[r] marks suppressor rows.
// ---------------------------------------------------------------------------
__global__ __launch_bounds__(256) void iou_kernel(
    const float4* __restrict__ topBoxes, u64* __restrict__ sup,
    unsigned char* __restrict__ rowNZ)
{
    int gid = blockIdx.x * 256 + threadIdx.x;
    int wid = gid >> 6;
    int lane = gid & 63;
    int b = wid / TOPN;
    int r = wid - b * TOPN;

    float4 A = topBoxes[(size_t)b * NPAD + r];
    float areaA = (A.z - A.x) * (A.w - A.y);
    size_t supBase = ((size_t)b * NPAD + r) * NW;

    u64 msave = 0, anyM = 0;
    for (int w = r >> 6; w < NW; ++w) {
        int j = w * 64 + lane;
        float4 Bx = topBoxes[(size_t)b * NPAD + j];
        float ix1 = fmaxf(A.x, Bx.x);
        float iy1 = fmaxf(A.y, Bx.y);
        float ix2 = fminf(A.z, Bx.z);
        float iy2 = fminf(A.w, Bx.w);
        float iw = fmaxf(ix2 - ix1, 0.0f);
        float ih = fmaxf(iy2 - iy1, 0.0f);
        float inter = iw * ih;
        float areaB = (Bx.z - Bx.x) * (Bx.w - Bx.y);
        float iou = inter / (areaA + areaB - inter + EPSF);
        bool s = (iou > IOU_T) && (j > r) && (j < TOPN);
        u64 m = __ballot(s);
        anyM |= m;
        if (lane == w) msave = m;     // lane w owns word w (w < 32)
    }
    if (lane == 0) rowNZ[(size_t)b * NPAD + r] = anyM ? 1 : 0;
    if (anyM && lane < NW) sup[supBase + lane] = msave;   // 256 B coalesced
}

// ---------------------------------------------------------------------------
// 4) Word-blocked NMS sweep, rowNZ-gated. nzmap[32] (bit r64 = row has any
//    suppression) is packed once from rowNZ; tile staging loads ONLY nz rows
//    (zeros otherwise -> garbage-safe vs iou's conditional stores), phase 2
//    gated by keep & nzmap. Double-buffered tiles + 1-ahead prefetch,
//    lgkm-only barriers, scalar ffs chain over kept in-word suppressors.
// ---------------------------------------------------------------------------
__global__ __launch_bounds__(256) void resolve_kernel(
    const u64* __restrict__ sup, const unsigned char* __restrict__ rowNZ,
    const float4* __restrict__ topBoxes, float4* __restrict__ out)
{
    int b = blockIdx.x;
    int tid = threadIdx.x;
    __shared__ u64 tile[2][64 * TSTRIDE];   // 2 x 16.9 KB
    __shared__ u64 keep[NW];
    __shared__ u64 nzmap[NW];
    __shared__ unsigned char nzbytes[256];
    __shared__ int wbase[NW];
    if (tid < NW) keep[tid] = (tid < 31) ? ~0ull : 0xFFFFull;  // bits >=2000 off
    const u64* supB = sup + (size_t)b * NPAD * NW;
    const unsigned char* nzB = rowNZ + (size_t)b * NPAD;
    unsigned* keep32 = (unsigned*)keep;

    // ---- pack rowNZ into nzmap[32] (bit r-64w of word w = row 64w+r nz) ----
    {
        u64 v = ((const u64*)nzB)[tid];      // rows 8*tid .. 8*tid+7
        u32 bits = 0;
#pragma unroll
        for (int q = 0; q < 8; ++q)
            bits |= (((v >> (8 * q)) & 0xFFull) ? 1u : 0u) << q;
        nzbytes[tid] = (unsigned char)bits;
    }
    __syncthreads();
    if (tid < NW) nzmap[tid] = ((const u64*)nzbytes)[tid];
    __syncthreads();

    int row = tid >> 2;               // 0..63
    int wcol = (tid & 3) * 8;         // base word within row (8 consecutive)

    // prologue: stage tile 0 (nz rows loaded, others zeroed)
    {
        uint4 p0 = make_uint4(0, 0, 0, 0), p1 = p0, p2 = p0, p3 = p0;
        if ((nzmap[0] >> row) & 1ull) {
            const uint4* src = (const uint4*)(supB + tid * 8);
            p0 = src[0]; p1 = src[1]; p2 = src[2]; p3 = src[3];
        }
        u64* d = &tile[0][row * TSTRIDE + wcol];
        d[0] = ((u64)p0.y << 32) | p0.x;  d[1] = ((u64)p0.w << 32) | p0.z;
        d[2] = ((u64)p1.y << 32) | p1.x;  d[3] = ((u64)p1.w << 32) | p1.z;
        d[4] = ((u64)p2.y << 32) | p2.x;  d[5] = ((u64)p2.w << 32) | p2.z;
        d[6] = ((u64)p3.y << 32) | p3.x;  d[7] = ((u64)p3.w << 32) | p3.z;
    }
    bar_lds();

    for (int w = 0; w < NW; ++w) {
        int buf = w & 1;
        // issue next tile's loads early (stay in flight across both barriers)
        uint4 n0 = make_uint4(0, 0, 0, 0), n1 = n0, n2 = n0, n3 = n0;
        if (w + 1 < NW && ((nzmap[w + 1] >> row) & 1ull)) {
            const uint4* src = (const uint4*)(supB + (size_t)(w + 1) * 2048 + tid * 8);
            n0 = src[0]; n1 = src[1]; n2 = src[2]; n3 = src[3];
        }

        // phase 1: wave 0 — scalar ffs chain over kept in-word suppressors.
        if (tid < 64) {
            u64 m = tile[buf][tid * TSTRIDE + w];
            u64 nzDiag = __ballot(m != 0ull);            // rows acting in-word
            u32 mlo = (u32)m, mhi = (u32)(m >> 32);
            u64 kw64 = keep[w];
            u32 kwlo = (u32)__builtin_amdgcn_readfirstlane((int)(u32)kw64);
            u32 kwhi = (u32)__builtin_amdgcn_readfirstlane((int)(u32)(kw64 >> 32));
            u64 kw = ((u64)kwhi << 32) | kwlo;
            u64 rem = kw & nzDiag;          // kept bits that suppress in-word
            while (rem) {
                int t2 = (int)(__ffsll((unsigned long long)rem) - 1);
                u32 alo = (u32)__builtin_amdgcn_readlane((int)mlo, t2);
                u32 ahi = (u32)__builtin_amdgcn_readlane((int)mhi, t2);
                u64 mt = ((u64)ahi << 32) | alo;   // bits strictly > t2 only
                kw &= ~mt;
                rem &= ~(mt | (1ull << t2));
            }
            if (tid == 0) keep[w] = kw;
        }
        bar_lds();

        // phase 2: apply kept suppressor rows to later words (from LDS)
        u64 gate = keep[w] & nzmap[w];
        int w2 = tid & 31;
        int grp = tid >> 5;              // 8 rows per thread
        if (w2 > w && gate) {
            u64 acc = 0;
#pragma unroll
            for (int q = 0; q < 8; ++q) {
                int rl = grp * 8 + q;
                if ((gate >> rl) & 1ull)
                    acc |= tile[buf][rl * TSTRIDE + w2];
            }
            if (acc) {
                u32 lo = (u32)acc, hi = (u32)(acc >> 32);
                if (lo) atomicAnd(&keep32[2 * w2], ~lo);
                if (hi) atomicAnd(&keep32[2 * w2 + 1], ~hi);
            }
        }

        // stage next tile into the alternate buffer (all rows written:
        // zero rows clear stale contents)
        if (w + 1 < NW) {
            u64* d = &tile[buf ^ 1][row * TSTRIDE + wcol];
            d[0] = ((u64)n0.y << 32) | n0.x;  d[1] = ((u64)n0.w << 32) | n0.z;
            d[2] = ((u64)n1.y << 32) | n1.x;  d[3] = ((u64)n1.w << 32) | n1.z;
            d[4] = ((u64)n2.y << 32) | n2.x;  d[5] = ((u64)n2.w << 32) | n2.z;
            d[6] = ((u64)n3.y << 32) | n3.x;  d[7] = ((u64)n3.w << 32) | n3.z;
        }
        bar_lds();
    }

    if (tid == 0) {
        int s = 0;
        for (int w2 = 0; w2 < NW; ++w2) { wbase[w2] = s; s += __popcll(keep[w2]); }
    }
    __syncthreads();
    for (int i = tid; i < TOPN; i += 256)
        out[(size_t)b * TOPN + i] = make_float4(0, 0, 0, 0);
    __syncthreads();
    for (int i = tid; i < TOPN; i += 256) {
        int wi = i >> 6, bz = i & 63;
        u64 kw = keep[wi];
        if ((kw >> bz) & 1ull) {
            int pos = wbase[wi] + __popcll(kw & ((1ull << bz) - 1ull));
            out[(size_t)b * TOPN + pos] = topBoxes[(size_t)b * NPAD + i];
        }
    }
}

// ---------------------------------------------------------------------------
// Workspace layout (bytes):
//   sup      : 0           size 8*2048*32*8 = 4,194,304
//   keys     : 4,194,304   size 8*36864*4   = 1,179,648
//   topBoxes : 5,373,952   size 8*2048*16   =   262,144
//   ghist    : 5,636,096   size 8*4096*4    =   131,072  (zeroed each call)
//   rowNZ    : 5,767,168   size 8*2048*1    =    16,384  (fully rewritten)
//   total    : 5,783,552 (~5.5 MB)
// ---------------------------------------------------------------------------
extern "C" void kernel_launch(void* const* d_in, const int* in_sizes, int n_in,
                              void* d_out, int out_size, void* d_ws, size_t ws_size,
                              hipStream_t stream)
{
    const float*  scores  = (const float*)d_in[0];
    const float4* offsets = (const float4*)d_in[1];
    const float*  anchors = (const float*)d_in[2];
    float4* out = (float4*)d_out;

    char* ws = (char*)d_ws;
    u64*           sup      = (u64*)(ws);
    u32*           keys     = (u32*)(ws + 4194304);
    float4*        topBoxes = (float4*)(ws + 5373952);
    u32*           ghist    = (u32*)(ws + 5636096);
    unsigned char* rowNZ    = (unsigned char*)(ws + 5767168);

    zero_kernel<<<(131072 / 16 + 255) / 256, 256, 0, stream>>>((uint4*)ghist, 131072 / 16);
    decode_kernel<<<(BATCH * NBOX) / 256, 256, 0, stream>>>(scores, offsets, anchors, keys, ghist);
    select_kernel<<<BATCH, 1024, 0, stream>>>(keys, ghist, scores, offsets, anchors, topBoxes);
    iou_kernel<<<(BATCH * TOPN * 64) / 256, 256, 0, stream>>>(topBoxes, sup, rowNZ);
    resolve_kernel<<<BATCH, 256, 0, stream>>>(sup, rowNZ, topBoxes, out);
}